// Round 1
// 882.493 us; speedup vs baseline: 1.1933x; 1.1933x over previous
//
#include <hip/hip_runtime.h>
#include <math.h>
#include <stdint.h>

typedef unsigned short u16;
typedef __bf16 bf16x8 __attribute__((ext_vector_type(8)));
typedef float f32x4 __attribute__((ext_vector_type(4)));

constexpr int Tq = 2048;
constexpr int D  = 1024;
constexpr int NHc = 16;
constexpr int Bc = 2;
constexpr int Mrows = Bc * Tq;   // 4096

__device__ __forceinline__ float wsum(float v){
#pragma unroll
  for(int o=32;o;o>>=1) v += __shfl_xor(v,o);
  return v;
}
__device__ __forceinline__ u16 f2bf(float f){          // RNE fp32->bf16
  union{ float f; unsigned u; } v; v.f = f;
  unsigned r = v.u + 0x7fffu + ((v.u >> 16) & 1u);
  return (u16)(r >> 16);
}
__device__ __forceinline__ float bf2f(u16 b){
  union{ unsigned u; float f; } v; v.u = ((unsigned)b) << 16;
  return v.f;
}
__device__ __forceinline__ void gl2lds16(const void* g, void* l){
  // async global->LDS, 16B/lane; LDS dst = wave-uniform base + lane*16
  __builtin_amdgcn_global_load_lds(
      (const __attribute__((address_space(1))) unsigned int*)g,
      (__attribute__((address_space(3))) unsigned int*)l, 16, 0, 0);
}

// ---------------- fp32 -> bf16 bulk convert (weights) -----------------------
__global__ __launch_bounds__(256) void cvt_kernel(const float* __restrict__ s,
                                                  u16* __restrict__ d){
  const int i = blockIdx.x*256 + threadIdx.x;
  const float4 v = ((const float4*)s)[i];
  ushort4 o; o.x=f2bf(v.x); o.y=f2bf(v.y); o.z=f2bf(v.z); o.w=f2bf(v.w);
  ((ushort4*)d)[i] = o;
}

// ---------------- LayerNorm: one block per row, bf16 out --------------------
__global__ __launch_bounds__(256) void ln_kernel(const float* __restrict__ x,
    const float* __restrict__ g, const float* __restrict__ b,
    u16* __restrict__ xn){
  const int row = blockIdx.x;
  const int tid = threadIdx.x;
  const float4 v = ((const float4*)(x + (size_t)row*D))[tid];
  float s = v.x+v.y+v.z+v.w;
  float q = v.x*v.x+v.y*v.y+v.z*v.z+v.w*v.w;
  s = wsum(s); q = wsum(q);
  __shared__ float sb[4], qb[4];
  if((tid&63)==0){ sb[tid>>6]=s; qb[tid>>6]=q; }
  __syncthreads();
  const float ts = sb[0]+sb[1]+sb[2]+sb[3];
  const float tq = qb[0]+qb[1]+qb[2]+qb[3];
  const float mu   = ts*(1.0f/D);
  const float var  = tq*(1.0f/D) - mu*mu;
  const float rstd = rsqrtf(var + 1e-5f);
  const float4 gv = ((const float4*)g)[tid];
  const float4 bv = ((const float4*)b)[tid];
  ushort4 o;
  o.x = f2bf((v.x-mu)*rstd*gv.x + bv.x);
  o.y = f2bf((v.y-mu)*rstd*gv.y + bv.y);
  o.z = f2bf((v.z-mu)*rstd*gv.z + bv.z);
  o.w = f2bf((v.w-mu)*rstd*gv.w + bv.w);
  ((ushort4*)(xn + (size_t)row*D))[tid] = o;
}

// ---------------- bf16 MFMA NT GEMM: C = A @ B^T ---------------------------
// A (M,K) row-major bf16, B (N,K) row-major bf16. 128x128 tile, BK=32,
// 256 thr = 4 waves in 2x2, each wave 64x64 = 4x4 MFMA 16x16x32 tiles.
// MODE 0: out bf16 (+optional fp32 bias)
// MODE 1: out fp32 + bias + residual
template<int MODE>
__global__ __launch_bounds__(256) void gemm_bf16(
    const u16* __restrict__ A, const u16* __restrict__ B, void* __restrict__ Cv,
    const float* __restrict__ bias, const float* __restrict__ resid,
    int K, int lda, int ldb, int ldc){
  __shared__ __align__(16) u16 As[128*32];
  __shared__ __align__(16) u16 Bs[128*32];
  const int tid  = threadIdx.x;
  const int lane = tid & 63, wv = tid >> 6;
  const int wRow = (wv >> 1) * 64, wCol = (wv & 1) * 64;
  const int mBase = blockIdx.y*128, nBase = blockIdx.x*128;
  const int quad = lane >> 4, r16 = lane & 15;
  const int sRow = lane >> 2;            // staging row within 16-row chunk
  const int sCol = (lane & 3) * 8;       // staging k-offset (elements)
  const char* smemA = (const char*)As;
  const char* smemB = (const char*)Bs;

  f32x4 acc[4][4];
#pragma unroll
  for(int i=0;i<4;i++)
#pragma unroll
    for(int j=0;j<4;j++) acc[i][j] = (f32x4)(0.f);

  for(int k0=0;k0<K;k0+=32){
#pragma unroll
    for(int rdn=0;rdn<2;rdn++){
      const int row = rdn*64 + wv*16 + sRow;
      gl2lds16(A + (size_t)(mBase + row)*lda + k0 + sCol,
               (void*)((char*)As + rdn*4096 + wv*1024));
      gl2lds16(B + (size_t)(nBase + row)*ldb + k0 + sCol,
               (void*)((char*)Bs + rdn*4096 + wv*1024));
    }
    __syncthreads();
    bf16x8 af[4], bfr[4];
#pragma unroll
    for(int i=0;i<4;i++)
      af[i]  = *(const bf16x8*)(smemA + (wRow + i*16 + r16)*64 + quad*16);
#pragma unroll
    for(int j=0;j<4;j++)
      bfr[j] = *(const bf16x8*)(smemB + (wCol + j*16 + r16)*64 + quad*16);
#pragma unroll
    for(int i=0;i<4;i++)
#pragma unroll
      for(int j=0;j<4;j++)
        acc[i][j] = __builtin_amdgcn_mfma_f32_16x16x32_bf16(af[i], bfr[j], acc[i][j], 0,0,0);
    __syncthreads();
  }

  // epilogue: C/D layout col=lane&15, row=quad*4+reg
#pragma unroll
  for(int i=0;i<4;i++){
#pragma unroll
    for(int j=0;j<4;j++){
      const int n = nBase + wCol + j*16 + r16;
      if(MODE==0){
        u16* C = (u16*)Cv;
        const float bv = bias ? bias[n] : 0.f;
#pragma unroll
        for(int reg=0;reg<4;reg++){
          const int m = mBase + wRow + i*16 + quad*4 + reg;
          C[(size_t)m*ldc + n] = f2bf(acc[i][j][reg] + bv);
        }
      } else {
        float* C = (float*)Cv;
        const float bv = bias[n];
#pragma unroll
        for(int reg=0;reg<4;reg++){
          const int m = mBase + wRow + i*16 + quad*4 + reg;
          C[(size_t)m*ldc + n] = acc[i][j][reg] + bv + resid[(size_t)m*ldc + n];
        }
      }
    }
  }
}

// ---------------- RoPE (split-half), in place on bf16 q1,k1 -----------------
__global__ __launch_bounds__(256) void rope_kernel(u16* __restrict__ q,
                                                   u16* __restrict__ k){
  const int idx = blockIdx.x*256 + threadIdx.x;
  const int m = idx >> 9;
  const int r = idx & 511;
  const int h = r >> 5, i = r & 31;
  const int t = m & (Tq-1);
  const float inv_freq = powf(10000.0f, -(float)i*(1.0f/32.0f));
  const float ang = (float)t * inv_freq;
  const float c = cosf(ang), s = sinf(ang);
  const size_t base = (size_t)m*D + h*64 + i;
  const float a0=bf2f(q[base]), a1=bf2f(q[base+32]);
  q[base]    = f2bf(a0*c - a1*s);
  q[base+32] = f2bf(a1*c + a0*s);
  const float b0=bf2f(k[base]), b1=bf2f(k[base+32]);
  k[base]    = f2bf(b0*c - b1*s);
  k[base+32] = f2bf(b1*c + b0*s);
}

// ---------------- transpose V: (B,T,D) bf16 -> (BH,64,T) bf16 ---------------
__global__ __launch_bounds__(256) void transpose_v(const u16* __restrict__ v2,
                                                   u16* __restrict__ Vt){
  __shared__ u16 tile[64][65];
  const int bt = blockIdx.x;        // t tile
  const int bh = blockIdx.y;
  const int b = bh >> 4, h = bh & 15;
  const int tid = threadIdx.x;
  const int t0 = bt*64;
#pragma unroll
  for(int rep=0;rep<4;rep++){
    const int tl = rep*16 + (tid>>4);
    const int dl = (tid&15)*4;
    const ushort4 val = *(const ushort4*)(v2 + (size_t)((size_t)b*Tq + t0 + tl)*D + h*64 + dl);
    tile[tl][dl+0]=val.x; tile[tl][dl+1]=val.y; tile[tl][dl+2]=val.z; tile[tl][dl+3]=val.w;
  }
  __syncthreads();
#pragma unroll
  for(int rep=0;rep<4;rep++){
    const int dl = rep*16 + (tid>>4);
    const int tl = (tid&15)*4;
    ushort4 o;
    o.x=tile[tl+0][dl]; o.y=tile[tl+1][dl]; o.z=tile[tl+2][dl]; o.w=tile[tl+3][dl];
    *(ushort4*)(Vt + ((size_t)bh*64 + dl)*Tq + t0 + tl) = o;
  }
}

// ---------------- fused attention: scores + softmax + PV --------------------
// Per block: one 128-row q tile of one (b,h). Two-pass flash:
//   pass 1: S = 0.125 * Q K^T tile-by-tile -> online row max m, row sum l
//   pass 2: recompute S, P = exp(S-m)/l, write P (fp32, full causal half)
//           to attnW, and accumulate O = P V via an LDS P round-trip.
// attnW columns right of the causal range are zero-filled up front.
// 4 waves; wave w owns q rows [w*32, w*32+32). MFMA 16x16x32 bf16.
__global__ __launch_bounds__(256, 2) void attn_fused(
    const u16* __restrict__ q2, const u16* __restrict__ k2,
    const u16* __restrict__ Vt, float* __restrict__ attnW,
    u16* __restrict__ O){
  constexpr int PSS = 40;                       // P-stage row stride (u16)
  __shared__ __align__(16) u16 Ks[2*128*32];    // [kk][128 rows][32 k] 16KB
  __shared__ __align__(16) u16 Vs[4*64*32];     // [chunk][64 d][32 t]  16KB
  __shared__ __align__(16) u16 QPs[2*128*32];   // Q tiles; reused as P stage

  // XCD-aware decode: linear id n -> (tRow, bh); all 16 tRow-blocks of a
  // 4-head group land on one XCD so K/V/Q slices stay L2-resident.
  const int n    = blockIdx.x + 16*blockIdx.y;  // 0..511
  const int tRow = (n >> 3) & 15;
  const int bh   = (n & 7) + 8*(n >> 7);
  const int b = bh >> 4, h = bh & 15;
  const int tid = threadIdx.x, lane = tid & 63, w = tid >> 6;
  const int quad = lane >> 4, r16 = lane & 15;
  const u16* Qg = q2 + ((size_t)b*Tq + (size_t)tRow*128)*D + h*64;
  const u16* Kg = k2 + ((size_t)b*Tq)*D + h*64;
  const u16* Vg = Vt + (size_t)bh*64*Tq;
  float* Wg = attnW + (size_t)bh*Tq*Tq + (size_t)tRow*128*Tq;

  // 1) zero non-causal columns (fire-and-forget; drains during pass 1)
  for(int ct2 = tRow+1; ct2 < Tq/128; ++ct2){
#pragma unroll
    for(int it=0; it<16; ++it){
      const int r = it*8 + (tid>>5);
      ((f32x4*)(Wg + (size_t)r*Tq + ct2*128))[tid & 31] = (f32x4)(0.f);
    }
  }

  // 2) stage Q once -> registers
#pragma unroll
  for(int rep=0; rep<4; ++rep){
    const int kb = rep*4 + w;
    const int kk = kb >> 3, row = (kb&7)*16 + (lane>>2);
    gl2lds16(Qg + (size_t)row*D + kk*32 + (lane&3)*8,
             (void*)((char*)QPs + kb*1024));
  }
  __syncthreads();
  bf16x8 af[2][2];
#pragma unroll
  for(int i=0;i<2;i++)
#pragma unroll
    for(int kk=0;kk<2;kk++)
      af[i][kk] = *(const bf16x8*)((const char*)QPs + kk*8192
                    + (w*32 + i*16 + r16)*64 + quad*16);

  float m[2][4], l[2][4];
#pragma unroll
  for(int i=0;i<2;i++)
#pragma unroll
    for(int rg=0;rg<4;rg++){ m[i][rg] = -1e30f; l[i][rg] = 0.f; }

  // -------- pass 1: stats --------
  for(int ct=0; ct<=tRow; ++ct){
#pragma unroll
    for(int rep=0; rep<4; ++rep){
      const int kb = rep*4 + w;
      const int kk = kb >> 3, row = (kb&7)*16 + (lane>>2);
      gl2lds16(Kg + ((size_t)ct*128 + row)*D + kk*32 + (lane&3)*8,
               (void*)((char*)Ks + kb*1024));
    }
    __syncthreads();
    f32x4 acc[2][8];
#pragma unroll
    for(int i=0;i<2;i++)
#pragma unroll
      for(int j=0;j<8;j++) acc[i][j] = (f32x4)(0.f);
#pragma unroll
    for(int kk=0;kk<2;kk++){
#pragma unroll
      for(int j=0;j<8;j++){
        const bf16x8 bfj = *(const bf16x8*)((const char*)Ks + kk*8192
                             + (j*16 + r16)*64 + quad*16);
#pragma unroll
        for(int i=0;i<2;i++)
          acc[i][j] = __builtin_amdgcn_mfma_f32_16x16x32_bf16(af[i][kk], bfj, acc[i][j],0,0,0);
      }
    }
    const bool diag = (ct == tRow);
#pragma unroll
    for(int i=0;i<2;i++){
#pragma unroll
      for(int rg=0; rg<4; ++rg){
        const int rowg = w*32 + i*16 + quad*4 + rg;
        float sv[8]; float mx = -1e30f;
#pragma unroll
        for(int j=0;j<8;j++){
          float s = acc[i][j][rg]*0.125f;
          if(diag && (j*16 + r16) > rowg) s = -1e30f;
          sv[j]=s; mx = fmaxf(mx,s);
        }
#pragma unroll
        for(int o=8;o;o>>=1) mx = fmaxf(mx, __shfl_xor(mx,o));
        const float mn = fmaxf(m[i][rg], mx);
        float ls = 0.f;
#pragma unroll
        for(int j=0;j<8;j++) ls += __expf(sv[j]-mn);
#pragma unroll
        for(int o=8;o;o>>=1) ls += __shfl_xor(ls,o);
        l[i][rg] = l[i][rg]*__expf(m[i][rg]-mn) + ls;
        m[i][rg] = mn;
      }
    }
    __syncthreads();
  }

  float rinv[2][4];
#pragma unroll
  for(int i=0;i<2;i++)
#pragma unroll
    for(int rg=0;rg<4;rg++) rinv[i][rg] = 1.0f / l[i][rg];
  f32x4 oacc[2][4];
#pragma unroll
  for(int i=0;i<2;i++)
#pragma unroll
    for(int j=0;j<4;j++) oacc[i][j] = (f32x4)(0.f);

  char* psb = (char*)QPs + w*(32*PSS*2);        // per-wave P stage

  // -------- pass 2: write P + accumulate O --------
  for(int ct=0; ct<=tRow; ++ct){
#pragma unroll
    for(int rep=0; rep<4; ++rep){
      const int kb = rep*4 + w;
      const int kk = kb >> 3, row = (kb&7)*16 + (lane>>2);
      gl2lds16(Kg + ((size_t)ct*128 + row)*D + kk*32 + (lane&3)*8,
               (void*)((char*)Ks + kb*1024));
      const int vrow = w*16 + (lane>>2);
      gl2lds16(Vg + (size_t)vrow*Tq + ct*128 + rep*32 + (lane&3)*8,
               (void*)((char*)Vs + (rep*4 + w)*1024));
    }
    __syncthreads();
    f32x4 acc[2][8];
#pragma unroll
    for(int i=0;i<2;i++)
#pragma unroll
      for(int j=0;j<8;j++) acc[i][j] = (f32x4)(0.f);
#pragma unroll
    for(int kk=0;kk<2;kk++){
#pragma unroll
      for(int j=0;j<8;j++){
        const bf16x8 bfj = *(const bf16x8*)((const char*)Ks + kk*8192
                             + (j*16 + r16)*64 + quad*16);
#pragma unroll
        for(int i=0;i<2;i++)
          acc[i][j] = __builtin_amdgcn_mfma_f32_16x16x32_bf16(af[i][kk], bfj, acc[i][j],0,0,0);
      }
    }
    const bool diag = (ct == tRow);
#pragma unroll
    for(int c=0;c<4;c++){                        // 32-k chunk of this tile
#pragma unroll
      for(int i=0;i<2;i++){
#pragma unroll
        for(int jj=0;jj<2;jj++){
          const int j = c*2 + jj;
#pragma unroll
          for(int rg=0;rg<4;rg++){
            const int rowl = i*16 + quad*4 + rg;
            const int rowg = w*32 + rowl;
            float s = acc[i][j][rg]*0.125f;
            if(diag && (j*16 + r16) > rowg) s = -1e30f;
            const float p = __expf(s - m[i][rg]) * rinv[i][rg];
            Wg[(size_t)rowg*Tq + ct*128 + j*16 + r16] = p;
            *(u16*)(psb + rowl*(PSS*2) + (jj*16 + r16)*2) = f2bf(p);
          }
        }
      }
      asm volatile("s_waitcnt lgkmcnt(0)" ::: "memory");
      __builtin_amdgcn_sched_barrier(0);
      bf16x8 pa[2];
#pragma unroll
      for(int i=0;i<2;i++)
        pa[i] = *(const bf16x8*)(psb + (i*16 + r16)*(PSS*2) + quad*16);
#pragma unroll
      for(int j2=0;j2<4;j2++){
        const bf16x8 bv = *(const bf16x8*)((const char*)Vs + c*4096
                            + (j2*16 + r16)*64 + quad*16);
        oacc[0][j2] = __builtin_amdgcn_mfma_f32_16x16x32_bf16(pa[0], bv, oacc[0][j2],0,0,0);
        oacc[1][j2] = __builtin_amdgcn_mfma_f32_16x16x32_bf16(pa[1], bv, oacc[1][j2],0,0,0);
      }
      asm volatile("s_waitcnt lgkmcnt(0)" ::: "memory");   // pa reads done
      __builtin_amdgcn_sched_barrier(0);                   // before overwrite
    }
    __syncthreads();
  }

  // O (bf16, (B,T,D) layout)
#pragma unroll
  for(int i=0;i<2;i++)
#pragma unroll
    for(int j2=0;j2<4;j2++)
#pragma unroll
      for(int rg=0;rg<4;rg++){
        const int trow = tRow*128 + w*32 + i*16 + quad*4 + rg;
        O[((size_t)b*Tq + trow)*D + h*64 + j2*16 + r16] = f2bf(oacc[i][j2][rg]);
      }
}

extern "C" void kernel_launch(void* const* d_in, const int* in_sizes, int n_in,
                              void* d_out, int out_size, void* d_ws, size_t ws_size,
                              hipStream_t stream){
  const float* x    = (const float*)d_in[0];
  const float* Win  = (const float*)d_in[1];   // (3072,1024)
  const float* bin  = (const float*)d_in[2];   // (3072)
  const float* Wout = (const float*)d_in[3];   // (1024,1024)
  const float* bout = (const float*)d_in[4];   // (1024)
  const float* gam  = (const float*)d_in[5];
  const float* bet  = (const float*)d_in[6];

  float* out   = (float*)d_out;
  float* attnW = out + (size_t)Mrows*D;        // (B,H,T,T) fp32

  // ws layout (bytes), 64 MB total:
  const size_t MB = 1u<<20;
  char* ws = (char*)d_ws;
  u16* Winb  = (u16*)(ws + 0);        // 6 MB (3M bf16)
  u16* Woutb = (u16*)(ws + 6*MB);     // 2 MB
  u16* xn    = (u16*)(ws + 8*MB);     // 8 MB  -> reused as Vt
  u16* Vt    = xn;
  u16* q1    = (u16*)(ws + 16*MB);    // 8 MB  -> reused as O
  u16* Oat   = q1;
  u16* k1    = (u16*)(ws + 24*MB);
  u16* v1    = (u16*)(ws + 32*MB);
  u16* q2    = (u16*)(ws + 40*MB);
  u16* k2    = (u16*)(ws + 48*MB);
  u16* v2    = (u16*)(ws + 56*MB);

  const size_t DD = (size_t)D*D;

  // 0) weight conversion fp32 -> bf16
  cvt_kernel<<<(3*DD/4)/256, 256, 0, stream>>>(Win, Winb);
  cvt_kernel<<<(DD/4)/256, 256, 0, stream>>>(Wout, Woutb);

  // 1) LayerNorm -> bf16
  ln_kernel<<<Mrows, 256, 0, stream>>>(x, gam, bet, xn);

  // 2) first projection (+bias): q1,k1,v1 bf16
  const dim3 gp(D/128, Mrows/128, 1);   // (8,32)
  gemm_bf16<0><<<gp,256,0,stream>>>(xn, Winb,        q1, bin,      nullptr, D, D, D, D);
  gemm_bf16<0><<<gp,256,0,stream>>>(xn, Winb+DD,     k1, bin+D,    nullptr, D, D, D, D);
  gemm_bf16<0><<<gp,256,0,stream>>>(xn, Winb+2*DD,   v1, bin+2*D,  nullptr, D, D, D, D);

  // 3) RoPE in place on q1,k1
  rope_kernel<<<(Mrows*512)/256, 256, 0, stream>>>(q1, k1);

  // 4) second projection (no bias): q2,k2,v2 bf16
  gemm_bf16<0><<<gp,256,0,stream>>>(q1, Winb,        q2, nullptr, nullptr, D, D, D, D);
  gemm_bf16<0><<<gp,256,0,stream>>>(k1, Winb+DD,     k2, nullptr, nullptr, D, D, D, D);
  gemm_bf16<0><<<gp,256,0,stream>>>(v1, Winb+2*DD,   v2, nullptr, nullptr, D, D, D, D);

  // 5) transpose V -> (BH,64,T)
  transpose_v<<<dim3(Tq/64, Bc*NHc), 256, 0, stream>>>(v2, Vt);

  // 6) fused scores + softmax + PV: writes attnW (fp32, incl. zero upper
  //    triangle) once and O (bf16) directly.
  attn_fused<<<dim3(Tq/128, Bc*NHc), 256, 0, stream>>>(q2, k2, Vt, attnW, Oat);

  // 7) out projection + bias + residual (fp32 out)
  gemm_bf16<1><<<gp,256,0,stream>>>(Oat, Woutb, out, bout, x, D, D, D, D);
}

// Round 2
// 796.242 us; speedup vs baseline: 1.3226x; 1.1083x over previous
//
#include <hip/hip_runtime.h>
#include <math.h>
#include <stdint.h>

typedef unsigned short u16;
typedef __bf16 bf16x8 __attribute__((ext_vector_type(8)));
typedef float f32x4 __attribute__((ext_vector_type(4)));

constexpr int Tq = 2048;
constexpr int D  = 1024;
constexpr int NHc = 16;
constexpr int Bc = 2;
constexpr int Mrows = Bc * Tq;   // 4096

__device__ __forceinline__ float wsum(float v){
#pragma unroll
  for(int o=32;o;o>>=1) v += __shfl_xor(v,o);
  return v;
}
__device__ __forceinline__ u16 f2bf(float f){          // RNE fp32->bf16
  union{ float f; unsigned u; } v; v.f = f;
  unsigned r = v.u + 0x7fffu + ((v.u >> 16) & 1u);
  return (u16)(r >> 16);
}
__device__ __forceinline__ float bf2f(u16 b){
  union{ unsigned u; float f; } v; v.u = ((unsigned)b) << 16;
  return v.f;
}
__device__ __forceinline__ void gl2lds16(const void* g, void* l){
  // async global->LDS, 16B/lane; LDS dst = wave-uniform base + lane*16
  __builtin_amdgcn_global_load_lds(
      (const __attribute__((address_space(1))) unsigned int*)g,
      (__attribute__((address_space(3))) unsigned int*)l, 16, 0, 0);
}

// ---------------- fp32 -> bf16 bulk convert (weights) -----------------------
__global__ __launch_bounds__(256) void cvt_kernel(const float* __restrict__ s,
                                                  u16* __restrict__ d){
  const int i = blockIdx.x*256 + threadIdx.x;
  const float4 v = ((const float4*)s)[i];
  ushort4 o; o.x=f2bf(v.x); o.y=f2bf(v.y); o.z=f2bf(v.z); o.w=f2bf(v.w);
  ((ushort4*)d)[i] = o;
}

// ---------------- LayerNorm: one block per row, bf16 out --------------------
__global__ __launch_bounds__(256) void ln_kernel(const float* __restrict__ x,
    const float* __restrict__ g, const float* __restrict__ b,
    u16* __restrict__ xn){
  const int row = blockIdx.x;
  const int tid = threadIdx.x;
  const float4 v = ((const float4*)(x + (size_t)row*D))[tid];
  float s = v.x+v.y+v.z+v.w;
  float q = v.x*v.x+v.y*v.y+v.z*v.z+v.w*v.w;
  s = wsum(s); q = wsum(q);
  __shared__ float sb[4], qb[4];
  if((tid&63)==0){ sb[tid>>6]=s; qb[tid>>6]=q; }
  __syncthreads();
  const float ts = sb[0]+sb[1]+sb[2]+sb[3];
  const float tq = qb[0]+qb[1]+qb[2]+qb[3];
  const float mu   = ts*(1.0f/D);
  const float var  = tq*(1.0f/D) - mu*mu;
  const float rstd = rsqrtf(var + 1e-5f);
  const float4 gv = ((const float4*)g)[tid];
  const float4 bv = ((const float4*)b)[tid];
  ushort4 o;
  o.x = f2bf((v.x-mu)*rstd*gv.x + bv.x);
  o.y = f2bf((v.y-mu)*rstd*gv.y + bv.y);
  o.z = f2bf((v.z-mu)*rstd*gv.z + bv.z);
  o.w = f2bf((v.w-mu)*rstd*gv.w + bv.w);
  ((ushort4*)(xn + (size_t)row*D))[tid] = o;
}

// ---------------- rotary cos/sin table: (T, 32) float2 ----------------------
__global__ __launch_bounds__(256) void rope_tab_kernel(float2* __restrict__ tab){
  const int idx = blockIdx.x*256 + threadIdx.x;   // T*32 = 65536
  const int t = idx >> 5, fi = idx & 31;
  const float inv = powf(10000.0f, -(float)fi*(1.0f/32.0f));
  const float ang = (float)t * inv;
  tab[idx] = make_float2(cosf(ang), sinf(ang));
}

// ---------------- merged proj-1: [q|k|v] = xn @ Win^T + bin, RoPE fused -----
// A (M,1024) bf16, B (3072,1024) bf16. Grid (24, 32). Output stacked
// (3, Mrows, 1024) bf16; for q/k slices the rotary rotation is applied
// in-register on the fp32 accumulators (pair (hp, hp+32) = (j, j+2)).
__global__ __launch_bounds__(256) void gemm_qkv1(
    const u16* __restrict__ A, const u16* __restrict__ B,
    const float* __restrict__ bias, const float2* __restrict__ tab,
    u16* __restrict__ out){
  __shared__ __align__(16) u16 As[128*32];
  __shared__ __align__(16) u16 Bs[128*32];
  const int tid  = threadIdx.x;
  const int lane = tid & 63, wv = tid >> 6;
  const int wRow = (wv >> 1) * 64, wCol = (wv & 1) * 64;
  const int mBase = blockIdx.y*128, nBase = blockIdx.x*128;
  const int quad = lane >> 4, r16 = lane & 15;
  const int sRow = lane >> 2;
  const int sCol = (lane & 3) * 8;
  const char* smemA = (const char*)As;
  const char* smemB = (const char*)Bs;

  f32x4 acc[4][4];
#pragma unroll
  for(int i=0;i<4;i++)
#pragma unroll
    for(int j=0;j<4;j++) acc[i][j] = (f32x4)(0.f);

  for(int k0=0;k0<D;k0+=32){
#pragma unroll
    for(int rdn=0;rdn<2;rdn++){
      const int row = rdn*64 + wv*16 + sRow;
      gl2lds16(A + (size_t)(mBase + row)*D + k0 + sCol,
               (void*)((char*)As + rdn*4096 + wv*1024));
      gl2lds16(B + (size_t)(nBase + row)*D + k0 + sCol,
               (void*)((char*)Bs + rdn*4096 + wv*1024));
    }
    __syncthreads();
    bf16x8 af[4], bfr[4];
#pragma unroll
    for(int i=0;i<4;i++)
      af[i]  = *(const bf16x8*)(smemA + (wRow + i*16 + r16)*64 + quad*16);
#pragma unroll
    for(int j=0;j<4;j++)
      bfr[j] = *(const bf16x8*)(smemB + (wCol + j*16 + r16)*64 + quad*16);
#pragma unroll
    for(int i=0;i<4;i++)
#pragma unroll
      for(int j=0;j<4;j++)
        acc[i][j] = __builtin_amdgcn_mfma_f32_16x16x32_bf16(af[i], bfr[j], acc[i][j], 0,0,0);
    __syncthreads();
  }

  const int sel  = nBase >> 10;          // 0=q 1=k 2=v (tiles never straddle)
  const int nLoc = nBase & 1023;
  u16* C = out + (size_t)sel*Mrows*D;
  if(sel < 2){
#pragma unroll
    for(int i=0;i<4;i++){
#pragma unroll
      for(int jp=0;jp<2;jp++){
        const int hp  = jp*16 + r16;           // 0..31 within head
        const int col = nLoc + wCol + hp;
        const float bv0 = bias[nBase + wCol + hp];
        const float bv1 = bias[nBase + wCol + hp + 32];
#pragma unroll
        for(int reg=0;reg<4;reg++){
          const int mm = mBase + wRow + i*16 + quad*4 + reg;
          const float2 cs = tab[((mm & (Tq-1))<<5) + hp];
          const float a0 = acc[i][jp][reg]   + bv0;
          const float a1 = acc[i][jp+2][reg] + bv1;
          C[(size_t)mm*D + col]      = f2bf(a0*cs.x - a1*cs.y);
          C[(size_t)mm*D + col + 32] = f2bf(a1*cs.x + a0*cs.y);
        }
      }
    }
  } else {
#pragma unroll
    for(int i=0;i<4;i++){
#pragma unroll
      for(int j=0;j<4;j++){
        const int n = nBase + wCol + j*16 + r16;
        const float bv = bias[n];
        const int col = nLoc + wCol + j*16 + r16;
#pragma unroll
        for(int reg=0;reg<4;reg++){
          const int mm = mBase + wRow + i*16 + quad*4 + reg;
          C[(size_t)mm*D + col] = f2bf(acc[i][j][reg] + bv);
        }
      }
    }
  }
}

// ---------------- merged proj-2: block-diagonal stacked GEMM ----------------
// A = stacked (3, Mrows, 1024) bf16; weight slice chosen by blockIdx.y>>5.
// C = stacked (3, Mrows, 1024) bf16. Grid (8, 96).
__global__ __launch_bounds__(256) void gemm_stack3(
    const u16* __restrict__ A, const u16* __restrict__ Bw,
    u16* __restrict__ C){
  __shared__ __align__(16) u16 As[128*32];
  __shared__ __align__(16) u16 Bs[128*32];
  const int wsel = blockIdx.y >> 5;
  const u16* B = Bw + (size_t)wsel*D*D;
  const int tid  = threadIdx.x;
  const int lane = tid & 63, wv = tid >> 6;
  const int wRow = (wv >> 1) * 64, wCol = (wv & 1) * 64;
  const int mBase = blockIdx.y*128, nBase = blockIdx.x*128;
  const int quad = lane >> 4, r16 = lane & 15;
  const int sRow = lane >> 2;
  const int sCol = (lane & 3) * 8;
  const char* smemA = (const char*)As;
  const char* smemB = (const char*)Bs;

  f32x4 acc[4][4];
#pragma unroll
  for(int i=0;i<4;i++)
#pragma unroll
    for(int j=0;j<4;j++) acc[i][j] = (f32x4)(0.f);

  for(int k0=0;k0<D;k0+=32){
#pragma unroll
    for(int rdn=0;rdn<2;rdn++){
      const int row = rdn*64 + wv*16 + sRow;
      gl2lds16(A + (size_t)(mBase + row)*D + k0 + sCol,
               (void*)((char*)As + rdn*4096 + wv*1024));
      gl2lds16(B + (size_t)(nBase + row)*D + k0 + sCol,
               (void*)((char*)Bs + rdn*4096 + wv*1024));
    }
    __syncthreads();
    bf16x8 af[4], bfr[4];
#pragma unroll
    for(int i=0;i<4;i++)
      af[i]  = *(const bf16x8*)(smemA + (wRow + i*16 + r16)*64 + quad*16);
#pragma unroll
    for(int j=0;j<4;j++)
      bfr[j] = *(const bf16x8*)(smemB + (wCol + j*16 + r16)*64 + quad*16);
#pragma unroll
    for(int i=0;i<4;i++)
#pragma unroll
      for(int j=0;j<4;j++)
        acc[i][j] = __builtin_amdgcn_mfma_f32_16x16x32_bf16(af[i], bfr[j], acc[i][j], 0,0,0);
    __syncthreads();
  }

#pragma unroll
  for(int i=0;i<4;i++){
#pragma unroll
    for(int j=0;j<4;j++){
      const int n = nBase + wCol + j*16 + r16;
#pragma unroll
      for(int reg=0;reg<4;reg++){
        const int mm = mBase + wRow + i*16 + quad*4 + reg;
        C[(size_t)mm*D + n] = f2bf(acc[i][j][reg]);
      }
    }
  }
}

// ---------------- out projection: fp32 + bias + residual --------------------
__global__ __launch_bounds__(256) void gemm_out(
    const u16* __restrict__ A, const u16* __restrict__ B, float* __restrict__ C,
    const float* __restrict__ bias, const float* __restrict__ resid){
  __shared__ __align__(16) u16 As[128*32];
  __shared__ __align__(16) u16 Bs[128*32];
  const int tid  = threadIdx.x;
  const int lane = tid & 63, wv = tid >> 6;
  const int wRow = (wv >> 1) * 64, wCol = (wv & 1) * 64;
  const int mBase = blockIdx.y*128, nBase = blockIdx.x*128;
  const int quad = lane >> 4, r16 = lane & 15;
  const int sRow = lane >> 2;
  const int sCol = (lane & 3) * 8;
  const char* smemA = (const char*)As;
  const char* smemB = (const char*)Bs;

  f32x4 acc[4][4];
#pragma unroll
  for(int i=0;i<4;i++)
#pragma unroll
    for(int j=0;j<4;j++) acc[i][j] = (f32x4)(0.f);

  for(int k0=0;k0<D;k0+=32){
#pragma unroll
    for(int rdn=0;rdn<2;rdn++){
      const int row = rdn*64 + wv*16 + sRow;
      gl2lds16(A + (size_t)(mBase + row)*D + k0 + sCol,
               (void*)((char*)As + rdn*4096 + wv*1024));
      gl2lds16(B + (size_t)(nBase + row)*D + k0 + sCol,
               (void*)((char*)Bs + rdn*4096 + wv*1024));
    }
    __syncthreads();
    bf16x8 af[4], bfr[4];
#pragma unroll
    for(int i=0;i<4;i++)
      af[i]  = *(const bf16x8*)(smemA + (wRow + i*16 + r16)*64 + quad*16);
#pragma unroll
    for(int j=0;j<4;j++)
      bfr[j] = *(const bf16x8*)(smemB + (wCol + j*16 + r16)*64 + quad*16);
#pragma unroll
    for(int i=0;i<4;i++)
#pragma unroll
      for(int j=0;j<4;j++)
        acc[i][j] = __builtin_amdgcn_mfma_f32_16x16x32_bf16(af[i], bfr[j], acc[i][j], 0,0,0);
    __syncthreads();
  }

#pragma unroll
  for(int i=0;i<4;i++){
#pragma unroll
    for(int j=0;j<4;j++){
      const int n = nBase + wCol + j*16 + r16;
      const float bv = bias[n];
#pragma unroll
      for(int reg=0;reg<4;reg++){
        const int mm = mBase + wRow + i*16 + quad*4 + reg;
        C[(size_t)mm*D + n] = acc[i][j][reg] + bv + resid[(size_t)mm*D + n];
      }
    }
  }
}

// ---------------- transpose V: (B,T,D) bf16 -> (BH,64,T) bf16 ---------------
__global__ __launch_bounds__(256) void transpose_v(const u16* __restrict__ v2,
                                                   u16* __restrict__ Vt){
  __shared__ u16 tile[64][65];
  const int bt = blockIdx.x;        // t tile
  const int bh = blockIdx.y;
  const int b = bh >> 4, h = bh & 15;
  const int tid = threadIdx.x;
  const int t0 = bt*64;
#pragma unroll
  for(int rep=0;rep<4;rep++){
    const int tl = rep*16 + (tid>>4);
    const int dl = (tid&15)*4;
    const ushort4 val = *(const ushort4*)(v2 + (size_t)((size_t)b*Tq + t0 + tl)*D + h*64 + dl);
    tile[tl][dl+0]=val.x; tile[tl][dl+1]=val.y; tile[tl][dl+2]=val.z; tile[tl][dl+3]=val.w;
  }
  __syncthreads();
#pragma unroll
  for(int rep=0;rep<4;rep++){
    const int dl = rep*16 + (tid>>4);
    const int tl = (tid&15)*4;
    ushort4 o;
    o.x=tile[tl+0][dl]; o.y=tile[tl+1][dl]; o.z=tile[tl+2][dl]; o.w=tile[tl+3][dl];
    *(ushort4*)(Vt + ((size_t)bh*64 + dl)*Tq + t0 + tl) = o;
  }
}

// ---------------- fused attention: scores + softmax + PV --------------------
// Per block: one 128-row q tile of one (b,h). Two-pass flash:
//   pass 1: S = 0.125 * Q K^T tile-by-tile -> online row max m, row sum l
//   pass 2: recompute S, P = exp(S-m)/l, write P (fp32, full causal half)
//           to attnW, and accumulate O = P V via an LDS P round-trip.
// attnW columns right of the causal range are zero-filled up front.
// 4 waves; wave w owns q rows [w*32, w*32+32). MFMA 16x16x32 bf16.
__global__ __launch_bounds__(256, 2) void attn_fused(
    const u16* __restrict__ q2, const u16* __restrict__ k2,
    const u16* __restrict__ Vt, float* __restrict__ attnW,
    u16* __restrict__ O){
  constexpr int PSS = 40;                       // P-stage row stride (u16)
  __shared__ __align__(16) u16 Ks[2*128*32];    // [kk][128 rows][32 k] 16KB
  __shared__ __align__(16) u16 Vs[4*64*32];     // [chunk][64 d][32 t]  16KB
  __shared__ __align__(16) u16 QPs[2*128*32];   // Q tiles; reused as P stage

  // XCD-aware decode: linear id n -> (tRow, bh); all 16 tRow-blocks of a
  // 4-head group land on one XCD so K/V/Q slices stay L2-resident.
  const int n    = blockIdx.x + 16*blockIdx.y;  // 0..511
  const int tRow = (n >> 3) & 15;
  const int bh   = (n & 7) + 8*(n >> 7);
  const int b = bh >> 4, h = bh & 15;
  const int tid = threadIdx.x, lane = tid & 63, w = tid >> 6;
  const int quad = lane >> 4, r16 = lane & 15;
  const u16* Qg = q2 + ((size_t)b*Tq + (size_t)tRow*128)*D + h*64;
  const u16* Kg = k2 + ((size_t)b*Tq)*D + h*64;
  const u16* Vg = Vt + (size_t)bh*64*Tq;
  float* Wg = attnW + (size_t)bh*Tq*Tq + (size_t)tRow*128*Tq;

  // 1) zero non-causal columns (fire-and-forget; drains during pass 1)
  for(int ct2 = tRow+1; ct2 < Tq/128; ++ct2){
#pragma unroll
    for(int it=0; it<16; ++it){
      const int r = it*8 + (tid>>5);
      ((f32x4*)(Wg + (size_t)r*Tq + ct2*128))[tid & 31] = (f32x4)(0.f);
    }
  }

  // 2) stage Q once -> registers
#pragma unroll
  for(int rep=0; rep<4; ++rep){
    const int kb = rep*4 + w;
    const int kk = kb >> 3, row = (kb&7)*16 + (lane>>2);
    gl2lds16(Qg + (size_t)row*D + kk*32 + (lane&3)*8,
             (void*)((char*)QPs + kb*1024));
  }
  __syncthreads();
  bf16x8 af[2][2];
#pragma unroll
  for(int i=0;i<2;i++)
#pragma unroll
    for(int kk=0;kk<2;kk++)
      af[i][kk] = *(const bf16x8*)((const char*)QPs + kk*8192
                    + (w*32 + i*16 + r16)*64 + quad*16);

  float m[2][4], l[2][4];
#pragma unroll
  for(int i=0;i<2;i++)
#pragma unroll
    for(int rg=0;rg<4;rg++){ m[i][rg] = -1e30f; l[i][rg] = 0.f; }

  // -------- pass 1: stats --------
  for(int ct=0; ct<=tRow; ++ct){
#pragma unroll
    for(int rep=0; rep<4; ++rep){
      const int kb = rep*4 + w;
      const int kk = kb >> 3, row = (kb&7)*16 + (lane>>2);
      gl2lds16(Kg + ((size_t)ct*128 + row)*D + kk*32 + (lane&3)*8,
               (void*)((char*)Ks + kb*1024));
    }
    __syncthreads();
    f32x4 acc[2][8];
#pragma unroll
    for(int i=0;i<2;i++)
#pragma unroll
      for(int j=0;j<8;j++) acc[i][j] = (f32x4)(0.f);
#pragma unroll
    for(int kk=0;kk<2;kk++){
#pragma unroll
      for(int j=0;j<8;j++){
        const bf16x8 bfj = *(const bf16x8*)((const char*)Ks + kk*8192
                             + (j*16 + r16)*64 + quad*16);
#pragma unroll
        for(int i=0;i<2;i++)
          acc[i][j] = __builtin_amdgcn_mfma_f32_16x16x32_bf16(af[i][kk], bfj, acc[i][j],0,0,0);
      }
    }
    const bool diag = (ct == tRow);
#pragma unroll
    for(int i=0;i<2;i++){
#pragma unroll
      for(int rg=0; rg<4; ++rg){
        const int rowg = w*32 + i*16 + quad*4 + rg;
        float sv[8]; float mx = -1e30f;
#pragma unroll
        for(int j=0;j<8;j++){
          float s = acc[i][j][rg]*0.125f;
          if(diag && (j*16 + r16) > rowg) s = -1e30f;
          sv[j]=s; mx = fmaxf(mx,s);
        }
#pragma unroll
        for(int o=8;o;o>>=1) mx = fmaxf(mx, __shfl_xor(mx,o));
        const float mn = fmaxf(m[i][rg], mx);
        float ls = 0.f;
#pragma unroll
        for(int j=0;j<8;j++) ls += __expf(sv[j]-mn);
#pragma unroll
        for(int o=8;o;o>>=1) ls += __shfl_xor(ls,o);
        l[i][rg] = l[i][rg]*__expf(m[i][rg]-mn) + ls;
        m[i][rg] = mn;
      }
    }
    __syncthreads();
  }

  float rinv[2][4];
#pragma unroll
  for(int i=0;i<2;i++)
#pragma unroll
    for(int rg=0;rg<4;rg++) rinv[i][rg] = 1.0f / l[i][rg];
  f32x4 oacc[2][4];
#pragma unroll
  for(int i=0;i<2;i++)
#pragma unroll
    for(int j=0;j<4;j++) oacc[i][j] = (f32x4)(0.f);

  char* psb = (char*)QPs + w*(32*PSS*2);        // per-wave P stage

  // -------- pass 2: write P + accumulate O --------
  for(int ct=0; ct<=tRow; ++ct){
#pragma unroll
    for(int rep=0; rep<4; ++rep){
      const int kb = rep*4 + w;
      const int kk = kb >> 3, row = (kb&7)*16 + (lane>>2);
      gl2lds16(Kg + ((size_t)ct*128 + row)*D + kk*32 + (lane&3)*8,
               (void*)((char*)Ks + kb*1024));
      const int vrow = w*16 + (lane>>2);
      gl2lds16(Vg + (size_t)vrow*Tq + ct*128 + rep*32 + (lane&3)*8,
               (void*)((char*)Vs + (rep*4 + w)*1024));
    }
    __syncthreads();
    f32x4 acc[2][8];
#pragma unroll
    for(int i=0;i<2;i++)
#pragma unroll
      for(int j=0;j<8;j++) acc[i][j] = (f32x4)(0.f);
#pragma unroll
    for(int kk=0;kk<2;kk++){
#pragma unroll
      for(int j=0;j<8;j++){
        const bf16x8 bfj = *(const bf16x8*)((const char*)Ks + kk*8192
                             + (j*16 + r16)*64 + quad*16);
#pragma unroll
        for(int i=0;i<2;i++)
          acc[i][j] = __builtin_amdgcn_mfma_f32_16x16x32_bf16(af[i][kk], bfj, acc[i][j],0,0,0);
      }
    }
    const bool diag = (ct == tRow);
#pragma unroll
    for(int c=0;c<4;c++){                        // 32-k chunk of this tile
#pragma unroll
      for(int i=0;i<2;i++){
#pragma unroll
        for(int jj=0;jj<2;jj++){
          const int j = c*2 + jj;
#pragma unroll
          for(int rg=0;rg<4;rg++){
            const int rowl = i*16 + quad*4 + rg;
            const int rowg = w*32 + rowl;
            float s = acc[i][j][rg]*0.125f;
            if(diag && (j*16 + r16) > rowg) s = -1e30f;
            const float p = __expf(s - m[i][rg]) * rinv[i][rg];
            Wg[(size_t)rowg*Tq + ct*128 + j*16 + r16] = p;
            *(u16*)(psb + rowl*(PSS*2) + (jj*16 + r16)*2) = f2bf(p);
          }
        }
      }
      asm volatile("s_waitcnt lgkmcnt(0)" ::: "memory");
      __builtin_amdgcn_sched_barrier(0);
      bf16x8 pa[2];
#pragma unroll
      for(int i=0;i<2;i++)
        pa[i] = *(const bf16x8*)(psb + (i*16 + r16)*(PSS*2) + quad*16);
#pragma unroll
      for(int j2=0;j2<4;j2++){
        const bf16x8 bv = *(const bf16x8*)((const char*)Vs + c*4096
                            + (j2*16 + r16)*64 + quad*16);
        oacc[0][j2] = __builtin_amdgcn_mfma_f32_16x16x32_bf16(pa[0], bv, oacc[0][j2],0,0,0);
        oacc[1][j2] = __builtin_amdgcn_mfma_f32_16x16x32_bf16(pa[1], bv, oacc[1][j2],0,0,0);
      }
      asm volatile("s_waitcnt lgkmcnt(0)" ::: "memory");   // pa reads done
      __builtin_amdgcn_sched_barrier(0);                   // before overwrite
    }
    __syncthreads();
  }

  // O (bf16, (B,T,D) layout)
#pragma unroll
  for(int i=0;i<2;i++)
#pragma unroll
    for(int j2=0;j2<4;j2++)
#pragma unroll
      for(int rg=0;rg<4;rg++){
        const int trow = tRow*128 + w*32 + i*16 + quad*4 + rg;
        O[((size_t)b*Tq + trow)*D + h*64 + j2*16 + r16] = f2bf(oacc[i][j2][rg]);
      }
}

extern "C" void kernel_launch(void* const* d_in, const int* in_sizes, int n_in,
                              void* d_out, int out_size, void* d_ws, size_t ws_size,
                              hipStream_t stream){
  const float* x    = (const float*)d_in[0];
  const float* Win  = (const float*)d_in[1];   // (3072,1024)
  const float* bin  = (const float*)d_in[2];   // (3072)
  const float* Wout = (const float*)d_in[3];   // (1024,1024)
  const float* bout = (const float*)d_in[4];   // (1024)
  const float* gam  = (const float*)d_in[5];
  const float* bet  = (const float*)d_in[6];

  float* out   = (float*)d_out;
  float* attnW = out + (size_t)Mrows*D;        // (B,H,T,T) fp32

  // ws layout (bytes), 64 MB total:
  //  0.. 6 MB : Winb (bf16 3072x1024)
  //  6.. 8 MB : Woutb
  //  8..16 MB : xn  -> reused as Vt (xn dead after proj-1)
  // 16..40 MB : qkv1 stacked (3,M,1024) -> first 8 MB reused as O after proj-2
  // 40..64 MB : qkv2 stacked (3,M,1024); rope table overlaps its head
  //             (table dead before proj-2 writes qkv2)
  const size_t MB = 1u<<20;
  char* ws = (char*)d_ws;
  u16* Winb  = (u16*)(ws + 0);
  u16* Woutb = (u16*)(ws + 6*MB);
  u16* xn    = (u16*)(ws + 8*MB);
  u16* Vt    = xn;
  u16* qkv1  = (u16*)(ws + 16*MB);
  u16* Oat   = qkv1;
  u16* qkv2  = (u16*)(ws + 40*MB);
  float2* tab = (float2*)(ws + 40*MB);

  const size_t DD = (size_t)D*D;
  const u16* q2 = qkv2;
  const u16* k2 = qkv2 + (size_t)Mrows*D;
  const u16* v2 = qkv2 + 2*(size_t)Mrows*D;

  // 0) weight conversion fp32 -> bf16, rotary table
  cvt_kernel<<<(3*DD/4)/256, 256, 0, stream>>>(Win, Winb);
  cvt_kernel<<<(DD/4)/256, 256, 0, stream>>>(Wout, Woutb);
  rope_tab_kernel<<<(Tq*32)/256, 256, 0, stream>>>(tab);

  // 1) LayerNorm -> bf16
  ln_kernel<<<Mrows, 256, 0, stream>>>(x, gam, bet, xn);

  // 2) merged first projection (+bias) with fused RoPE -> qkv1 stacked
  gemm_qkv1<<<dim3(3*D/128, Mrows/128), 256, 0, stream>>>(xn, Winb, bin, tab, qkv1);

  // 3) merged second projection (block-diagonal, no bias) -> qkv2 stacked
  gemm_stack3<<<dim3(D/128, 3*Mrows/128), 256, 0, stream>>>(qkv1, Winb, qkv2);

  // 4) transpose V -> (BH,64,T)
  transpose_v<<<dim3(Tq/64, Bc*NHc), 256, 0, stream>>>(v2, Vt);

  // 5) fused scores + softmax + PV: writes attnW (fp32, incl. zero upper
  //    triangle) once and O (bf16) directly.
  attn_fused<<<dim3(Tq/128, Bc*NHc), 256, 0, stream>>>(q2, k2, Vt, attnW, Oat);

  // 6) out projection + bias + residual (fp32 out)
  gemm_out<<<dim3(D/128, Mrows/128), 256, 0, stream>>>(Oat, Woutb, out, bout, x);
}